// Round 12
// baseline (285.127 us; speedup 1.0000x reference)
//
#include <hip/hip_runtime.h>
#include <hip/hip_bf16.h>
#include <stdint.h>

#define SQF 0.70710678118654752f
#define SQ2 1.41421356237309505f

typedef __bf16 bf16x8 __attribute__((ext_vector_type(8)));
typedef float f32x4 __attribute__((ext_vector_type(4)));

using GLp = const __attribute__((address_space(1))) void*;
using LDp = __attribute__((address_space(3))) void*;

__device__ __forceinline__ unsigned short f2bf(float f) {
  union { float f; uint32_t u; } v; v.f = f;
  uint32_t r = v.u + 0x7fffu + ((v.u >> 16) & 1u);
  return (unsigned short)(r >> 16);
}
__device__ __forceinline__ float bf2f(unsigned short h) {
  union { uint32_t u; float f; } v; v.u = (uint32_t)h << 16; return v.f;
}

// ---------------- prepack conv_w -> Wp bf16 ----------------
// Layout: Wp[((ks*16 + cog)*64 + lane)*8 + e]:
//   co = cog*16 + (lane&15), ci = (ks&7)*32 + (lane>>4)*8 + e, k = ks>>3.
__global__ void prepack_w(const float* __restrict__ w, unsigned short* __restrict__ Wp) {
  int f = blockIdx.x * 256 + threadIdx.x;
  if (f >= 40 * 8192) return;
  int e = f & 7;
  int lane = (f >> 3) & 63;
  int cog = (f >> 9) & 15;
  int ks = f >> 13;
  int co = cog * 16 + (lane & 15);
  int ci = (ks & 7) * 32 + (lane >> 4) * 8 + e;
  int k = ks >> 3;
  Wp[f] = f2bf(w[(co * 256 + ci) * 5 + k]);
}

// ---------------- transpose + cast: x[b][ci][l] f32 -> xT[b][l][ci] bf16 ----------------
__global__ void transpose_x(const float* __restrict__ x, unsigned short* __restrict__ xT) {
  __shared__ __attribute__((aligned(16))) unsigned short Ts[64 * 72];
  const int lt = blockIdx.x, ct = blockIdx.y, b = blockIdx.z;
  const int t = threadIdx.x;
  const int l0 = lt * 64, ci0 = ct * 64;
#pragma unroll
  for (int p = 0; p < 4; ++p) {
    int cil = p * 16 + (t >> 4);
    int ll = (t & 15) * 4;
    const float4 v = *(const float4*)(x + (((size_t)b * 256 + ci0 + cil) * 16384 + l0 + ll));
    Ts[(ll + 0) * 72 + cil] = f2bf(v.x);
    Ts[(ll + 1) * 72 + cil] = f2bf(v.y);
    Ts[(ll + 2) * 72 + cil] = f2bf(v.z);
    Ts[(ll + 3) * 72 + cil] = f2bf(v.w);
  }
  __syncthreads();
#pragma unroll
  for (int p = 0; p < 4; ++p) {
    int ll = p * 16 + (t >> 4);
    int cq = (t & 15) * 4;
    ushort4 v = *(const ushort4*)(&Ts[ll * 72 + cq]);
    *(ushort4*)(xT + (((size_t)b * 16384 + l0 + ll) * 256 + ci0 + cq)) = v;
  }
}

// ---------------- main conv via MFMA bf16, 128co x 128l wave tile ----------------
// 128-thread block = 2 waves; wave w owns co [w*128, w*128+128) x l [l0, l0+128).
// Per K-step per wave: A 8 frags (8 KB, global L2-hot) + B 8 frags (8 KB LDS)
// feed 64 MFMAs -> 250 B/MFMA, 2x better than r11 (W-path was the measured wall).
// acc 256 + frags ~150 regs -> 1 wave/SIMD; K-loop barrier-free, ILP covers latency.
__global__ __launch_bounds__(128, 1)
void conv_mfma(const unsigned short* __restrict__ xT, const unsigned short* __restrict__ Wp,
               const float* __restrict__ bias, float* __restrict__ out) {
  __shared__ __attribute__((aligned(16))) unsigned short Xs[132 * 256];
  const int tid = threadIdx.x;
  const int lane = tid & 63;
  const int wm = tid >> 6;    // wave id = co group (128 each)
  const int lt = blockIdx.x;  // 128 l-tiles
  const int b = blockIdx.y;
  const int l0 = lt << 7;
  const int r15 = lane & 15, g = lane >> 4;

  // zero halo rows at batch edges (rows 0,1 / 130,131)
  if (lt == 0 && tid < 64) *(float4*)(&Xs[tid * 8]) = float4{0.f, 0.f, 0.f, 0.f};
  if (lt == 127 && tid < 64) *(float4*)(&Xs[130 * 256 + tid * 8]) = float4{0.f, 0.f, 0.f, 0.f};

  // stage X tile: 132 rows x 512B = 4224 16B-chunks = 33 iters x 128 thr,
  // global_load_lds 16B, source-swizzled so LDS stays linear
  {
    const size_t xbase = (size_t)b * 16384 * 256;
#pragma unroll
    for (int it = 0; it < 33; ++it) {
      int idx = it * 128 + tid;
      int row = idx >> 5, cl = idx & 31;
      int l = l0 - 2 + row;
      void* ldst = (void*)(Xs + ((idx & ~63) << 3));   // wave-uniform base
      if (l >= 0 && l < 16384) {
        const unsigned short* src = xT + xbase + (size_t)l * 256 + ((cl ^ (row & 7)) << 3);
        __builtin_amdgcn_global_load_lds((GLp)src, (LDp)ldst, 16, 0, 0);
      }
    }
  }

  auto loadA = [&](bf16x8* a, int ks) {
#pragma unroll
    for (int mf = 0; mf < 8; ++mf)
      a[mf] = *reinterpret_cast<const bf16x8*>(
          Wp + (size_t)ks * 8192 + ((wm * 8 + mf) << 9) + (lane << 3));
  };
  auto loadB = [&](bf16x8* bv, int ks) {
    const int k = ks >> 3, cb = ks & 7;
    const int c = cb * 4 + g;
    const int jb = r15 + k;
#pragma unroll
    for (int nf = 0; nf < 8; ++nf) {
      int j = jb + nf * 16;
      bv[nf] = *reinterpret_cast<const bf16x8*>(&Xs[j * 256 + ((c ^ (j & 7)) << 3)]);
    }
  };

  f32x4 acc[8][8];
#pragma unroll
  for (int mf = 0; mf < 8; ++mf)
#pragma unroll
    for (int nf = 0; nf < 8; ++nf) acc[mf][nf] = f32x4{0.f, 0.f, 0.f, 0.f};

  bf16x8 aA[8], aB[8], bA[8], bB[8];
  loadA(aA, 0);                 // A prefetch rides over the staging barrier
  __syncthreads();              // X tile resident
  loadB(bA, 0);

  for (int ks = 0; ks < 40; ks += 2) {
    loadA(aB, ks + 1);          // prefetch next while computing current
    loadB(bB, ks + 1);
#pragma unroll
    for (int mf = 0; mf < 8; ++mf)
#pragma unroll
      for (int nf = 0; nf < 8; ++nf)
        acc[mf][nf] = __builtin_amdgcn_mfma_f32_16x16x32_bf16(aA[mf], bA[nf], acc[mf][nf], 0, 0, 0);
    if (ks < 38) { loadA(aA, ks + 2); loadB(bA, ks + 2); }
#pragma unroll
    for (int mf = 0; mf < 8; ++mf)
#pragma unroll
      for (int nf = 0; nf < 8; ++nf)
        acc[mf][nf] = __builtin_amdgcn_mfma_f32_16x16x32_bf16(aB[mf], bB[nf], acc[mf][nf], 0, 0, 0);
  }

  // epilogue (pure store): D frag col(l)=lane&15, row(co)=(lane>>4)*4+reg
  const size_t ob = (size_t)b * 256 * 16384;
  const int lglob = l0 + r15;
#pragma unroll
  for (int mf = 0; mf < 8; ++mf) {
    int co0 = wm * 128 + mf * 16 + g * 4;
#pragma unroll
    for (int r = 0; r < 4; ++r) {
      float bv = bias[co0 + r];
#pragma unroll
      for (int nf = 0; nf < 8; ++nf)
        out[ob + (size_t)(co0 + r) * 16384 + lglob + nf * 16] = acc[mf][nf][r] + bv;
    }
  }
}

// ---------------- fallback naive conv (only if ws too small) ----------------
__global__ void conv_naive(const float* __restrict__ x, const float* __restrict__ w,
                           const float* __restrict__ bias, float* __restrict__ out) {
  int l = blockIdx.x * 256 + threadIdx.x;
  int co = blockIdx.y, b = blockIdx.z;
  float acc = bias[co];
  const float* xb = x + (size_t)b * 256 * 16384;
  const float* wr = w + (size_t)co * 256 * 5;
  for (int ci = 0; ci < 256; ++ci) {
    const float* xc = xb + (size_t)ci * 16384;
    const float* wc = wr + ci * 5;
#pragma unroll
    for (int k = 0; k < 5; ++k) {
      int j = l + k - 2;
      float v = (j >= 0 && j < 16384) ? xc[j] : 0.f;
      acc += wc[k] * v;
    }
  }
  out[((size_t)b * 256 + co) * 16384 + l] = acc;
}

// ---------------- fused wavelet path (runs LAST): out += scale * rec ----------------
// 1024 threads, 64 KB LDS -> 2 blocks/CU = 32 waves/CU.
#define OFF_D2  0
#define OFF_R1  4096
#define OFF_A3  8192
#define OFF_D3  10240
#define OFF_R2O 8192

__device__ __forceinline__ float conv5(const float* a, const float* w, int idx, int len) {
  if (idx >= len) return 0.f;
  float s = 0.f;
#pragma unroll
  for (int t = 0; t < 5; ++t) {
    int j = idx + t - 2;
    float v = (j >= 0 && j < len) ? a[j] : 0.f;
    s += w[t] * v;
  }
  return s;
}
__device__ __forceinline__ float conv5h(const unsigned short* a, const float* w, int idx, int len) {
  if (idx >= len) return 0.f;
  float s = 0.f;
#pragma unroll
  for (int t = 0; t < 5; ++t) {
    int j = idx + t - 2;
    float v = (j >= 0 && j < len) ? bf2f(a[j]) : 0.f;
    s += w[t] * v;
  }
  return s;
}

__global__ __launch_bounds__(1024, 2)
void wavelet_add(const float* __restrict__ x, const float* __restrict__ w0g,
                 const float* __restrict__ w1g, const float* __restrict__ w2g,
                 const float* __restrict__ scale, float* __restrict__ out) {
  __shared__ __attribute__((aligned(16))) unsigned short D1h[8192];  // bf16 D1
  __shared__ __attribute__((aligned(16))) float S[12288];
  const int t = threadIdx.x;           // 0..1023
  const int bc = blockIdx.x;
  const int c = bc & 255;
  const size_t rowbase = (size_t)bc * 16384;
  float w0[5], w1[5], w2[5];
#pragma unroll
  for (int i = 0; i < 5; ++i) { w0[i] = w0g[c * 5 + i]; w1[i] = w1g[c * 5 + i]; w2[i] = w2g[c * 5 + i]; }
  const float sc = scale[c];

  // ---- P1: fused 3-level Haar analysis; all 4 float4 loads issued eagerly
  {
    const float4* x4 = (const float4*)(x + rowbase);
    const int i0 = t, i1 = t + 1024;
    float4 u0 = x4[2 * i0];
    float4 v0 = x4[2 * i0 + 1];
    float4 u1 = x4[2 * i1];
    float4 v1 = x4[2 * i1 + 1];
#pragma unroll
    for (int s = 0; s < 2; ++s) {
      int i = s ? i1 : i0;
      float4 u = s ? u1 : u0;
      float4 v = s ? v1 : v0;
      float a10 = SQF * (u.x + u.y), d10 = SQF * (u.x - u.y);
      float a11 = SQF * (u.z + u.w), d11 = SQF * (u.z - u.w);
      float a12 = SQF * (v.x + v.y), d12 = SQF * (v.x - v.y);
      float a13 = SQF * (v.z + v.w), d13 = SQF * (v.z - v.w);
      uint32_t q0 = ((uint32_t)f2bf(d11) << 16) | f2bf(d10);
      uint32_t q1 = ((uint32_t)f2bf(d13) << 16) | f2bf(d12);
      *(uint2*)(&D1h[4 * i]) = uint2{q0, q1};
      float a20 = SQF * (a10 + a11), d20 = SQF * (a10 - a11);
      float a21 = SQF * (a12 + a13), d21 = SQF * (a12 - a13);
      *(float2*)(&S[OFF_D2 + 2 * i]) = float2{d20, d21};
      S[OFF_A3 + i] = SQF * (a20 + a21);
      S[OFF_D3 + i] = SQF * (a20 - a21);
    }
  }
  __syncthreads();
  // ---- P2: rec1 = idwt(A3, conv5(D3,w0)), i in [0,2048)
  {
    const float* A3 = &S[OFF_A3]; const float* D3 = &S[OFF_D3];
#pragma unroll
    for (int s = 0; s < 2; ++s) {
      int i = s * 1024 + t;
      float a3 = A3[i];
      float a3p = (i < 2047) ? A3[i + 1] : 0.f;
      float dc = conv5(D3, w0, i, 2048);
      float dcp = conv5(D3, w0, i + 1, 2048);
      *(float2*)(&S[OFF_R1 + 2 * i]) = float2{SQ2 * a3, SQF * (a3 + a3p + dc - dcp)};
    }
  }
  __syncthreads();
  // ---- P3: rec2 odd samples only (evens recomputed from R1); overlays A3|D3
  {
    const float* R1 = &S[OFF_R1]; const float* D2 = &S[OFF_D2];
#pragma unroll
    for (int s = 0; s < 4; ++s) {
      int i = s * 1024 + t;                // i in [0,4096)
      float r1 = R1[i];
      float r1p = (i < 4095) ? R1[i + 1] : 0.f;
      float dm = conv5(D2, w1, i, 4096);
      float dmp = conv5(D2, w1, i + 1, 4096);
      S[OFF_R2O + i] = SQF * (r1 + r1p + dm - dmp);
    }
  }
  __syncthreads();
  // ---- P4: rec3, float4 RMW into out (out lines L3-hot from conv's store)
  {
    const float* R1 = &S[OFF_R1]; const float* R2O = &S[OFF_R2O];
    float4* op = (float4*)(out + rowbase);
#pragma unroll
    for (int s = 0; s < 4; ++s) {
      int m = s * 1024 + t;                // m in [0,4096)
      float r1 = R1[m];
      float r1p = (m < 4095) ? R1[m + 1] : 0.f;
      float ro = R2O[m];
      float e0 = SQ2 * r1;                 // rec2[2m]
      float e1 = SQ2 * r1p;                // rec2[2m+2]
      float df0 = conv5h(D1h, w2, 2 * m, 8192);
      float df1 = conv5h(D1h, w2, 2 * m + 1, 8192);
      float df2 = conv5h(D1h, w2, 2 * m + 2, 8192);
      float4 cu = op[m];
      cu.x += sc * (SQ2 * e0);
      cu.y += sc * (SQF * (e0 + ro + df0 - df1));
      cu.z += sc * (SQ2 * ro);
      cu.w += sc * (SQF * (ro + e1 + df1 - df2));
      op[m] = cu;
    }
  }
}

extern "C" void kernel_launch(void* const* d_in, const int* in_sizes, int n_in,
                              void* d_out, int out_size, void* d_ws, size_t ws_size,
                              hipStream_t stream) {
  const float* x = (const float*)d_in[0];
  const float* conv_w = (const float*)d_in[1];
  const float* conv_b = (const float*)d_in[2];
  const float* w0 = (const float*)d_in[3];
  const float* w1 = (const float*)d_in[4];
  const float* w2 = (const float*)d_in[5];
  const float* scale = (const float*)d_in[6];
  float* out = (float*)d_out;

  const size_t XT_BYTES = 67108864ull;           // 8*16384*256 bf16
  const size_t WP_BYTES = 655360ull;             // 40*8192 bf16
  if (ws_size >= XT_BYTES + WP_BYTES) {
    unsigned short* xT = (unsigned short*)d_ws;
    unsigned short* Wp = (unsigned short*)((char*)d_ws + XT_BYTES);
    prepack_w<<<dim3(1280), dim3(256), 0, stream>>>(conv_w, Wp);
    transpose_x<<<dim3(256, 4, 8), dim3(256), 0, stream>>>(x, xT);
    conv_mfma<<<dim3(128, 8), dim3(128), 0, stream>>>(xT, Wp, conv_b, out);
  } else {
    conv_naive<<<dim3(64, 256, 8), dim3(256), 0, stream>>>(x, conv_w, conv_b, out);
  }
  wavelet_add<<<dim3(2048), dim3(1024), 0, stream>>>(x, w0, w1, w2, scale, out);
}

// Round 13
// 176.038 us; speedup vs baseline: 1.6197x; 1.6197x over previous
//
#include <hip/hip_runtime.h>
#include <hip/hip_bf16.h>
#include <stdint.h>

#define SQF 0.70710678118654752f
#define SQ2 1.41421356237309505f

typedef __bf16 bf16x8 __attribute__((ext_vector_type(8)));
typedef float f32x4 __attribute__((ext_vector_type(4)));

using GLp = const __attribute__((address_space(1))) void*;
using LDp = __attribute__((address_space(3))) void*;

__device__ __forceinline__ unsigned short f2bf(float f) {
  union { float f; uint32_t u; } v; v.f = f;
  uint32_t r = v.u + 0x7fffu + ((v.u >> 16) & 1u);
  return (unsigned short)(r >> 16);
}
__device__ __forceinline__ float bf2f(unsigned short h) {
  union { uint32_t u; float f; } v; v.u = (uint32_t)h << 16; return v.f;
}

// ---------------- prepack conv_w -> Wp bf16 ----------------
// Layout: Wp[((ks*16 + cog)*64 + lane)*8 + e]:
//   co = cog*16 + (lane&15), ci = (ks&7)*32 + (lane>>4)*8 + e, k = ks>>3.
__global__ void prepack_w(const float* __restrict__ w, unsigned short* __restrict__ Wp) {
  int f = blockIdx.x * 256 + threadIdx.x;
  if (f >= 40 * 8192) return;
  int e = f & 7;
  int lane = (f >> 3) & 63;
  int cog = (f >> 9) & 15;
  int ks = f >> 13;
  int co = cog * 16 + (lane & 15);
  int ci = (ks & 7) * 32 + (lane >> 4) * 8 + e;
  int k = ks >> 3;
  Wp[f] = f2bf(w[(co * 256 + ci) * 5 + k]);
}

// ---------------- transpose + cast: x[b][ci][l] f32 -> xT[b][l][ci] bf16 ----------------
__global__ void transpose_x(const float* __restrict__ x, unsigned short* __restrict__ xT) {
  __shared__ __attribute__((aligned(16))) unsigned short Ts[64 * 72];
  const int lt = blockIdx.x, ct = blockIdx.y, b = blockIdx.z;
  const int t = threadIdx.x;
  const int l0 = lt * 64, ci0 = ct * 64;
#pragma unroll
  for (int p = 0; p < 4; ++p) {
    int cil = p * 16 + (t >> 4);
    int ll = (t & 15) * 4;
    const float4 v = *(const float4*)(x + (((size_t)b * 256 + ci0 + cil) * 16384 + l0 + ll));
    Ts[(ll + 0) * 72 + cil] = f2bf(v.x);
    Ts[(ll + 1) * 72 + cil] = f2bf(v.y);
    Ts[(ll + 2) * 72 + cil] = f2bf(v.z);
    Ts[(ll + 3) * 72 + cil] = f2bf(v.w);
  }
  __syncthreads();
#pragma unroll
  for (int p = 0; p < 4; ++p) {
    int ll = p * 16 + (t >> 4);
    int cq = (t & 15) * 4;
    ushort4 v = *(const ushort4*)(&Ts[ll * 72 + cq]);
    *(ushort4*)(xT + (((size_t)b * 16384 + l0 + ll) * 256 + ci0 + cq)) = v;
  }
}

// ---------------- main conv via MFMA bf16 (frozen r7/r9 structure, 78 us) ----------------
// MODE 0: store f32 to out.  MODE 1: store bf16 to cres (wavelet finishes the sum).
template<int MODE>
__global__ __launch_bounds__(512, 4)
void conv_mfma(const unsigned short* __restrict__ xT, const unsigned short* __restrict__ Wp,
               const float* __restrict__ bias, float* __restrict__ out,
               unsigned short* __restrict__ cres) {
  __shared__ __attribute__((aligned(16))) unsigned short Xs[132 * 256];
  const int tid = threadIdx.x;
  const int lane = tid & 63;
  const int wv = tid >> 6;
  const int wm = wv & 3;      // co block (64 each)
  const int wn = wv >> 2;     // l block (64 each)
  const int lt = blockIdx.x;  // 128 l-tiles
  const int b = blockIdx.y;
  const int l0 = lt << 7;
  const int r15 = lane & 15, g = lane >> 4;

  // zero halo rows at batch edges (rows 0,1 / 130,131)
  if (lt == 0 && tid < 64) *(float4*)(&Xs[tid * 8]) = float4{0.f, 0.f, 0.f, 0.f};
  if (lt == 127 && tid < 64) *(float4*)(&Xs[130 * 256 + tid * 8]) = float4{0.f, 0.f, 0.f, 0.f};

  // stage X tile: 132 rows x 512B, global_load_lds 16B, source-swizzled so LDS stays linear
  {
    const size_t xbase = (size_t)b * 16384 * 256;
#pragma unroll
    for (int it = 0; it < 9; ++it) {
      int idx = it * 512 + tid;
      if (idx >= 132 * 32) break;          // cuts whole waves only
      int row = idx >> 5, cl = idx & 31;
      int l = l0 - 2 + row;
      void* ldst = (void*)(Xs + ((idx & ~63) << 3));   // wave-uniform base
      if (l >= 0 && l < 16384) {
        const unsigned short* src = xT + xbase + (size_t)l * 256 + ((cl ^ (row & 7)) << 3);
        __builtin_amdgcn_global_load_lds((GLp)src, (LDp)ldst, 16, 0, 0);
      }
    }
  }

  auto loadA = [&](bf16x8* a, int ks) {
#pragma unroll
    for (int mf = 0; mf < 4; ++mf)
      a[mf] = *reinterpret_cast<const bf16x8*>(
          Wp + (size_t)ks * 8192 + ((wm * 4 + mf) << 9) + (lane << 3));
  };
  auto loadB = [&](bf16x8* bv, int ks) {
    const int k = ks >> 3, cb = ks & 7;
    const int c = cb * 4 + g;
    const int jb = wn * 64 + r15 + k;
#pragma unroll
    for (int nf = 0; nf < 4; ++nf) {
      int j = jb + nf * 16;
      bv[nf] = *reinterpret_cast<const bf16x8*>(&Xs[j * 256 + ((c ^ (j & 7)) << 3)]);
    }
  };

  f32x4 acc[4][4];
#pragma unroll
  for (int mf = 0; mf < 4; ++mf)
#pragma unroll
    for (int nf = 0; nf < 4; ++nf) acc[mf][nf] = f32x4{0.f, 0.f, 0.f, 0.f};

  bf16x8 aA[4], aB[4], bfr[4];
  loadA(aA, 0);                 // A prefetch rides over the staging barrier
  __syncthreads();              // X tile resident

  for (int ks = 0; ks < 40; ks += 2) {
    loadA(aB, ks + 1);          // prefetch next A while computing with aA
    loadB(bfr, ks);
#pragma unroll
    for (int mf = 0; mf < 4; ++mf)
#pragma unroll
      for (int nf = 0; nf < 4; ++nf)
        acc[mf][nf] = __builtin_amdgcn_mfma_f32_16x16x32_bf16(aA[mf], bfr[nf], acc[mf][nf], 0, 0, 0);
    if (ks < 38) loadA(aA, ks + 2);
    loadB(bfr, ks + 1);
#pragma unroll
    for (int mf = 0; mf < 4; ++mf)
#pragma unroll
      for (int nf = 0; nf < 4; ++nf)
        acc[mf][nf] = __builtin_amdgcn_mfma_f32_16x16x32_bf16(aB[mf], bfr[nf], acc[mf][nf], 0, 0, 0);
  }

  // epilogue (pure store): D frag col(l)=lane&15, row(co)=(lane>>4)*4+reg
  const size_t ob = (size_t)b * 256 * 16384;
  const int lglob = l0 + wn * 64 + r15;
#pragma unroll
  for (int mf = 0; mf < 4; ++mf) {
    int co0 = wm * 64 + mf * 16 + g * 4;
#pragma unroll
    for (int r = 0; r < 4; ++r) {
      float bv = bias[co0 + r];
#pragma unroll
      for (int nf = 0; nf < 4; ++nf) {
        size_t o = ob + (size_t)(co0 + r) * 16384 + lglob + nf * 16;
        float v = acc[mf][nf][r] + bv;
        if (MODE == 0) out[o] = v;
        else           cres[o] = f2bf(v);
      }
    }
  }
}

// ---------------- fallback naive conv (only if ws too small) ----------------
__global__ void conv_naive(const float* __restrict__ x, const float* __restrict__ w,
                           const float* __restrict__ bias, float* __restrict__ out) {
  int l = blockIdx.x * 256 + threadIdx.x;
  int co = blockIdx.y, b = blockIdx.z;
  float acc = bias[co];
  const float* xb = x + (size_t)b * 256 * 16384;
  const float* wr = w + (size_t)co * 256 * 5;
  for (int ci = 0; ci < 256; ++ci) {
    const float* xc = xb + (size_t)ci * 16384;
    const float* wc = wr + ci * 5;
#pragma unroll
    for (int k = 0; k < 5; ++k) {
      int j = l + k - 2;
      float v = (j >= 0 && j < 16384) ? xc[j] : 0.f;
      acc += wc[k] * v;
    }
  }
  out[((size_t)b * 256 + co) * 16384 + l] = acc;
}

// ---------------- fused wavelet path (runs LAST) ----------------
// MODE 0: out += scale*rec (RMW).  MODE 1: out = bf2f(cres) + scale*rec (pure store).
// 1024 threads, 64 KB LDS -> 2 blocks/CU = 32 waves/CU.
#define OFF_D2  0
#define OFF_R1  4096
#define OFF_A3  8192
#define OFF_D3  10240
#define OFF_R2O 8192

__device__ __forceinline__ float conv5(const float* a, const float* w, int idx, int len) {
  if (idx >= len) return 0.f;
  float s = 0.f;
#pragma unroll
  for (int t = 0; t < 5; ++t) {
    int j = idx + t - 2;
    float v = (j >= 0 && j < len) ? a[j] : 0.f;
    s += w[t] * v;
  }
  return s;
}
__device__ __forceinline__ float conv5h(const unsigned short* a, const float* w, int idx, int len) {
  if (idx >= len) return 0.f;
  float s = 0.f;
#pragma unroll
  for (int t = 0; t < 5; ++t) {
    int j = idx + t - 2;
    float v = (j >= 0 && j < len) ? bf2f(a[j]) : 0.f;
    s += w[t] * v;
  }
  return s;
}

template<int MODE>
__global__ __launch_bounds__(1024, 2)
void wavelet_add(const float* __restrict__ x, const float* __restrict__ w0g,
                 const float* __restrict__ w1g, const float* __restrict__ w2g,
                 const float* __restrict__ scale, float* __restrict__ out,
                 const unsigned short* __restrict__ cres) {
  __shared__ __attribute__((aligned(16))) unsigned short D1h[8192];  // bf16 D1
  __shared__ __attribute__((aligned(16))) float S[12288];
  const int t = threadIdx.x;           // 0..1023
  const int bc = blockIdx.x;
  const int c = bc & 255;
  const size_t rowbase = (size_t)bc * 16384;
  float w0[5], w1[5], w2[5];
#pragma unroll
  for (int i = 0; i < 5; ++i) { w0[i] = w0g[c * 5 + i]; w1[i] = w1g[c * 5 + i]; w2[i] = w2g[c * 5 + i]; }
  const float sc = scale[c];

  // ---- P1: fused 3-level Haar analysis; all 4 float4 loads issued eagerly
  {
    const float4* x4 = (const float4*)(x + rowbase);
    const int i0 = t, i1 = t + 1024;
    float4 u0 = x4[2 * i0];
    float4 v0 = x4[2 * i0 + 1];
    float4 u1 = x4[2 * i1];
    float4 v1 = x4[2 * i1 + 1];
#pragma unroll
    for (int s = 0; s < 2; ++s) {
      int i = s ? i1 : i0;
      float4 u = s ? u1 : u0;
      float4 v = s ? v1 : v0;
      float a10 = SQF * (u.x + u.y), d10 = SQF * (u.x - u.y);
      float a11 = SQF * (u.z + u.w), d11 = SQF * (u.z - u.w);
      float a12 = SQF * (v.x + v.y), d12 = SQF * (v.x - v.y);
      float a13 = SQF * (v.z + v.w), d13 = SQF * (v.z - v.w);
      uint32_t q0 = ((uint32_t)f2bf(d11) << 16) | f2bf(d10);
      uint32_t q1 = ((uint32_t)f2bf(d13) << 16) | f2bf(d12);
      *(uint2*)(&D1h[4 * i]) = uint2{q0, q1};
      float a20 = SQF * (a10 + a11), d20 = SQF * (a10 - a11);
      float a21 = SQF * (a12 + a13), d21 = SQF * (a12 - a13);
      *(float2*)(&S[OFF_D2 + 2 * i]) = float2{d20, d21};
      S[OFF_A3 + i] = SQF * (a20 + a21);
      S[OFF_D3 + i] = SQF * (a20 - a21);
    }
  }
  __syncthreads();
  // ---- P2: rec1 = idwt(A3, conv5(D3,w0)), i in [0,2048)
  {
    const float* A3 = &S[OFF_A3]; const float* D3 = &S[OFF_D3];
#pragma unroll
    for (int s = 0; s < 2; ++s) {
      int i = s * 1024 + t;
      float a3 = A3[i];
      float a3p = (i < 2047) ? A3[i + 1] : 0.f;
      float dc = conv5(D3, w0, i, 2048);
      float dcp = conv5(D3, w0, i + 1, 2048);
      *(float2*)(&S[OFF_R1 + 2 * i]) = float2{SQ2 * a3, SQF * (a3 + a3p + dc - dcp)};
    }
  }
  __syncthreads();
  // ---- P3: rec2 odd samples only (evens recomputed from R1); overlays A3|D3
  {
    const float* R1 = &S[OFF_R1]; const float* D2 = &S[OFF_D2];
#pragma unroll
    for (int s = 0; s < 4; ++s) {
      int i = s * 1024 + t;                // i in [0,4096)
      float r1 = R1[i];
      float r1p = (i < 4095) ? R1[i + 1] : 0.f;
      float dm = conv5(D2, w1, i, 4096);
      float dmp = conv5(D2, w1, i + 1, 4096);
      S[OFF_R2O + i] = SQF * (r1 + r1p + dm - dmp);
    }
  }
  __syncthreads();
  // ---- P4: rec3 -> out. MODE1: out = convres(bf16, L3-hot) + sc*rec, pure float4 store.
  {
    const float* R1 = &S[OFF_R1]; const float* R2O = &S[OFF_R2O];
    float4* op = (float4*)(out + rowbase);
    const unsigned short* crow = cres + rowbase;
#pragma unroll
    for (int s = 0; s < 4; ++s) {
      int m = s * 1024 + t;                // m in [0,4096)
      float r1 = R1[m];
      float r1p = (m < 4095) ? R1[m + 1] : 0.f;
      float ro = R2O[m];
      float e0 = SQ2 * r1;                 // rec2[2m]
      float e1 = SQ2 * r1p;                // rec2[2m+2]
      float df0 = conv5h(D1h, w2, 2 * m, 8192);
      float df1 = conv5h(D1h, w2, 2 * m + 1, 8192);
      float df2 = conv5h(D1h, w2, 2 * m + 2, 8192);
      float4 cu;
      if (MODE == 0) {
        cu = op[m];
      } else {
        ushort4 cv = *(const ushort4*)(crow + 4 * m);
        cu = float4{bf2f(cv.x), bf2f(cv.y), bf2f(cv.z), bf2f(cv.w)};
      }
      cu.x += sc * (SQ2 * e0);
      cu.y += sc * (SQF * (e0 + ro + df0 - df1));
      cu.z += sc * (SQ2 * ro);
      cu.w += sc * (SQF * (ro + e1 + df1 - df2));
      op[m] = cu;
    }
  }
}

extern "C" void kernel_launch(void* const* d_in, const int* in_sizes, int n_in,
                              void* d_out, int out_size, void* d_ws, size_t ws_size,
                              hipStream_t stream) {
  const float* x = (const float*)d_in[0];
  const float* conv_w = (const float*)d_in[1];
  const float* conv_b = (const float*)d_in[2];
  const float* w0 = (const float*)d_in[3];
  const float* w1 = (const float*)d_in[4];
  const float* w2 = (const float*)d_in[5];
  const float* scale = (const float*)d_in[6];
  float* out = (float*)d_out;

  const size_t XT_BYTES = 67108864ull;           // 8*16384*256 bf16
  const size_t WP_BYTES = 655360ull;             // 40*8192 bf16
  const size_t CR_BYTES = 67108864ull;           // 8*256*16384 bf16 conv result
  if (ws_size >= XT_BYTES + WP_BYTES + CR_BYTES) {
    unsigned short* xT = (unsigned short*)d_ws;
    unsigned short* Wp = (unsigned short*)((char*)d_ws + XT_BYTES);
    unsigned short* cr = (unsigned short*)((char*)d_ws + XT_BYTES + WP_BYTES);
    prepack_w<<<dim3(1280), dim3(256), 0, stream>>>(conv_w, Wp);
    transpose_x<<<dim3(256, 4, 8), dim3(256), 0, stream>>>(x, xT);
    conv_mfma<1><<<dim3(128, 8), dim3(512), 0, stream>>>(xT, Wp, conv_b, out, cr);
    wavelet_add<1><<<dim3(2048), dim3(1024), 0, stream>>>(x, w0, w1, w2, scale, out, cr);
  } else if (ws_size >= XT_BYTES + WP_BYTES) {
    unsigned short* xT = (unsigned short*)d_ws;
    unsigned short* Wp = (unsigned short*)((char*)d_ws + XT_BYTES);
    prepack_w<<<dim3(1280), dim3(256), 0, stream>>>(conv_w, Wp);
    transpose_x<<<dim3(256, 4, 8), dim3(256), 0, stream>>>(x, xT);
    conv_mfma<0><<<dim3(128, 8), dim3(512), 0, stream>>>(xT, Wp, conv_b, out, nullptr);
    wavelet_add<0><<<dim3(2048), dim3(1024), 0, stream>>>(x, w0, w1, w2, scale, out, nullptr);
  } else {
    conv_naive<<<dim3(64, 256, 8), dim3(256), 0, stream>>>(x, conv_w, conv_b, out);
    wavelet_add<0><<<dim3(2048), dim3(1024), 0, stream>>>(x, w0, w1, w2, scale, out, nullptr);
  }
}